// Round 7
// baseline (44.014 us; speedup 1.0000x reference)
//
#include <hip/hip_runtime.h>
#include <stdint.h>

// QuantConv1D (binary, K=3, Cin=128, Cout=256, VALID) + bias + BN(inference)
// via XNOR-popcount on bit-packed signs.
//
// out(b,t,co) = p*A[co] + C[co], p = popc over 384 xor'd bits,
// A = -2/sqrt(var+eps), C = (384+bias-mean)/sqrt(var+eps) + beta.
//
// R4: wave-autonomous streaming (no LDS/barriers), float4 load = 2 rows,
//     ballot masks ARE the packed rows (wave-uniform, SGPRs).
// R6: nontemporal f32x4 stores.
// R7: occupancy push — TW=16 (8192 waves = 8/SIMD of work), 1-deep prefetch
//     2-output bodies (~82 VGPR), __launch_bounds__(256,6) to hold 6
//     waves/SIMD resident; 8 blocks/CU for tail balance.

#define B 64
#define T 2048
#define CIN 128
#define COUT 256
#define KW 3
#define TOUT (T - KW + 1)   // 2046
#define TW 16               // outputs per wave-window
#define NWIN 128            // windows per batch row; last overlaps (t0=2030)
#define WPB 4               // waves per block

typedef float f32x4 __attribute__((ext_vector_type(4)));

// ---- pass 1: pack kernel signs, transposed layout ----
// kbT[co*12 + k*4 + i], word i bit b <-> cin = 4b+i  (matches ballot order)
__global__ __launch_bounds__(256) void pack_w_kernel(const float* __restrict__ ker,
                                                     const float* __restrict__ bias,
                                                     const float* __restrict__ beta,
                                                     const float* __restrict__ mean,
                                                     const float* __restrict__ var,
                                                     uint32_t* __restrict__ kbT,
                                                     float* __restrict__ A,
                                                     float* __restrict__ C) {
    int k  = blockIdx.x >> 2;       // 0..2
    int i  = blockIdx.x & 3;        // word index 0..3
    int co = threadIdx.x;           // 0..255
    const float* src = ker + ((size_t)(k * CIN + i)) * COUT + co;
    uint32_t wbits = 0;
    #pragma unroll 8
    for (int bb = 0; bb < 32; ++bb) {
        if (src[(size_t)(4 * bb) * COUT] >= 0.0f) wbits |= (1u << bb);
    }
    kbT[(size_t)co * 12 + k * 4 + i] = wbits;
    if (blockIdx.x == 0) {
        float inv = 1.0f / sqrtf(var[co] + 1e-3f);
        A[co] = -2.0f * inv;
        C[co] = (384.0f + bias[co] - mean[co]) * inv + beta[co];
    }
}

__device__ __forceinline__ int popc4(uint32_t a0, uint32_t a1, uint32_t a2,
                                     uint32_t a3, uint4 k) {
    return __popc(a0 ^ k.x) + __popc(a1 ^ k.y) + __popc(a2 ^ k.z) + __popc(a3 ^ k.w);
}

// ---- pass 2: wave-autonomous fused pack-x + popcount conv + affine ----
__global__ __launch_bounds__(256, 6) void conv_kernel(const float* __restrict__ x,
                                                      const uint32_t* __restrict__ kbT,
                                                      const float* __restrict__ A,
                                                      const float* __restrict__ C,
                                                      float* __restrict__ out) {
    const int l   = threadIdx.x & 63;
    const int wv  = threadIdx.x >> 6;
    const int gw  = blockIdx.x * WPB + wv;          // 0..B*NWIN-1
    const int b   = gw >> 7;                        // /NWIN
    const int win = gw & (NWIN - 1);
    const int t0  = (win < NWIN - 1) ? win * TW : (TOUT - TW);  // last overlaps

    // per-thread kernel bits: kj[j][k] = 4 words for cout co0+j, tap k
    const int co0 = l * 4;
    uint4 kj[4][KW];
    #pragma unroll
    for (int j = 0; j < 4; ++j)
        #pragma unroll
        for (int k = 0; k < KW; ++k)
            kj[j][k] = *(const uint4*)(kbT + (size_t)(co0 + j) * 12 + k * 4);
    const float4 av = *(const float4*)(A + co0);
    const float4 cv = *(const float4*)(C + co0);

    // lane l covers row (l>=32) of each pair, cins (l%32)*4..+3
    const float* xb0 = x + (size_t)b * T * CIN;
    const int l4 = l * 4;
    auto loadpair = [&](int r) -> float4 {   // clamped (prefetch overrun ok)
        r = (r > T - 2) ? (T - 2) : r;
        return *(const float4*)(xb0 + (size_t)r * CIN + l4);
    };

    // prologue: pairs 0,1 (rows t0..t0+3)
    float4 v0 = loadpair(t0);
    float4 v  = loadpair(t0 + 2);
    uint64_t p0 = __ballot(v0.x >= 0.0f);
    uint64_t p1 = __ballot(v0.y >= 0.0f);
    uint64_t p2 = __ballot(v0.z >= 0.0f);
    uint64_t p3 = __ballot(v0.w >= 0.0f);

    float* orow = out + ((size_t)b * TOUT + t0) * COUT + co0;

    #pragma unroll 2
    for (int j = 0; j < TW / 2; ++j) {   // 8 bodies, 2 outputs each
        float4 vn = loadpair(t0 + 2 * j + 4);   // prefetch pair j+2

        uint64_t m0 = __ballot(v.x >= 0.0f);    // pair j+1: rows 2j+2, 2j+3
        uint64_t m1 = __ballot(v.y >= 0.0f);
        uint64_t m2 = __ballot(v.z >= 0.0f);
        uint64_t m3 = __ballot(v.w >= 0.0f);

        uint32_t r0a = (uint32_t)p0,         r0b = (uint32_t)p1,         r0c = (uint32_t)p2,         r0d = (uint32_t)p3;
        uint32_t r1a = (uint32_t)(p0 >> 32), r1b = (uint32_t)(p1 >> 32), r1c = (uint32_t)(p2 >> 32), r1d = (uint32_t)(p3 >> 32);
        uint32_t r2a = (uint32_t)m0,         r2b = (uint32_t)m1,         r2c = (uint32_t)m2,         r2d = (uint32_t)m3;
        uint32_t r3a = (uint32_t)(m0 >> 32), r3b = (uint32_t)(m1 >> 32), r3c = (uint32_t)(m2 >> 32), r3d = (uint32_t)(m3 >> 32);

        f32x4 o0, o1;
        #pragma unroll
        for (int jj = 0; jj < 4; ++jj) {
            int s0 = popc4(r0a, r0b, r0c, r0d, kj[jj][0])
                   + popc4(r1a, r1b, r1c, r1d, kj[jj][1])
                   + popc4(r2a, r2b, r2c, r2d, kj[jj][2]);
            int s1 = popc4(r1a, r1b, r1c, r1d, kj[jj][0])
                   + popc4(r2a, r2b, r2c, r2d, kj[jj][1])
                   + popc4(r3a, r3b, r3c, r3d, kj[jj][2]);
            float aj = (&av.x)[jj], cj = (&cv.x)[jj];
            o0[jj] = fmaf((float)s0, aj, cj);
            o1[jj] = fmaf((float)s1, aj, cj);
        }

        float* op = orow + (size_t)(2 * j) * COUT;
        __builtin_nontemporal_store(o0, (f32x4*)op);
        __builtin_nontemporal_store(o1, (f32x4*)(op + COUT));

        p0 = m0; p1 = m1; p2 = m2; p3 = m3;
        v = vn;
    }
}

extern "C" void kernel_launch(void* const* d_in, const int* in_sizes, int n_in,
                              void* d_out, int out_size, void* d_ws, size_t ws_size,
                              hipStream_t stream) {
    const float* x    = (const float*)d_in[0];
    const float* ker  = (const float*)d_in[1];
    const float* bias = (const float*)d_in[2];
    const float* beta = (const float*)d_in[3];
    const float* mean = (const float*)d_in[4];
    const float* var  = (const float*)d_in[5];
    float* out = (float*)d_out;

    // workspace: kbT (12 KB) | A (1 KB) | C (1 KB)
    uint32_t* kbT = (uint32_t*)d_ws;
    float*    A   = (float*)(kbT + (size_t)COUT * 12);
    float*    C   = A + COUT;

    pack_w_kernel<<<KW * 4, 256, 0, stream>>>(ker, bias, beta, mean, var, kbT, A, C);
    conv_kernel<<<(B * NWIN) / WPB, 256, 0, stream>>>(x, kbT, A, C, out);
}